// Round 1
// baseline (1620.027 us; speedup 1.0000x reference)
//
#include <hip/hip_runtime.h>

#define NN 200000
#define NB 32
#define NWG (NN / NB)   // 6250

typedef unsigned short u16;
typedef unsigned int u32;
typedef __attribute__((ext_vector_type(8))) short short8;
typedef __attribute__((ext_vector_type(4))) float f32x4;

__device__ __forceinline__ u16 f2bf(float x) {
  u32 u = __float_as_uint(x);
  u += 0x7FFFu + ((u >> 16) & 1u);
  return (u16)(u >> 16);
}
__device__ __forceinline__ float sigf(float x) {
  float e = __builtin_amdgcn_exp2f(x * -1.44269504f);
  return __builtin_amdgcn_rcpf(1.0f + e);
}
__device__ __forceinline__ float tanhf_(float x) {
  float e = __builtin_amdgcn_exp2f(x * 2.88539008f);
  return 1.0f - 2.0f * __builtin_amdgcn_rcpf(1.0f + e);
}

// msg[n][k] = bf16(feat[n][k] / out_norm[n]); 16 threads per row, 8 elems each
__global__ void k_prep_msg(const float* __restrict__ feat, const float* __restrict__ onorm,
                           u16* __restrict__ msg) {
  int i = blockIdx.x * 256 + threadIdx.x;   // 3,200,000 total, exact
  int row = i >> 4, c8 = (i & 15) * 8;
  const float4 a = *(const float4*)(feat + (size_t)row * 128 + c8);
  const float4 b = *(const float4*)(feat + (size_t)row * 128 + c8 + 4);
  float s = 1.0f / onorm[row];
  short8 v = { (short)f2bf(a.x * s), (short)f2bf(a.y * s), (short)f2bf(a.z * s), (short)f2bf(a.w * s),
               (short)f2bf(b.x * s), (short)f2bf(b.y * s), (short)f2bf(b.z * s), (short)f2bf(b.w * s) };
  *(short8*)(msg + (size_t)row * 128 + c8) = v;
}

__global__ void k_prep_w(const float* __restrict__ Wih, const float* __restrict__ Whh,
                         const float* __restrict__ Wlin, const float* __restrict__ bih,
                         const float* __restrict__ bhh, u16* __restrict__ wihb,
                         u16* __restrict__ whhb, u16* __restrict__ wlinb,
                         float* __restrict__ bsum) {
  int i = blockIdx.x * 256 + threadIdx.x;   // 147,968 total, exact
  if (i < 65536) wihb[i] = f2bf(Wih[i]);
  else if (i < 131072) whhb[i - 65536] = f2bf(Whh[i - 65536]);
  else if (i < 147456) wlinb[i - 131072] = f2bf(Wlin[i - 131072]);
  else { int j = i - 147456; bsum[j] = bih[j] + bhh[j]; }
}

__global__ void k_hist(const int* __restrict__ degs, int* __restrict__ hist, int n) {
  __shared__ int lh[33];
  if (threadIdx.x < 33) lh[threadIdx.x] = 0;
  __syncthreads();
  int i = blockIdx.x * 256 + threadIdx.x;
  if (i < n) atomicAdd(&lh[degs[i]], 1);
  __syncthreads();
  if (threadIdx.x < 33 && lh[threadIdx.x]) atomicAdd(&hist[threadIdx.x], lh[threadIdx.x]);
}

// descending-degree exclusive prefix (longest blocks scheduled first)
__global__ void k_scan(const int* __restrict__ hist, int* __restrict__ basep) {
  if (threadIdx.x == 0 && blockIdx.x == 0) {
    int a = 0;
    for (int d = 32; d >= 1; --d) { basep[d] = a; a += hist[d]; }
    basep[0] = a;
  }
}

__global__ void k_scatter(const int* __restrict__ degs, int* __restrict__ basep,
                          int* __restrict__ perm, int n) {
  int i = blockIdx.x * 256 + threadIdx.x;
  if (i < n) { int p = atomicAdd(&basep[degs[i]], 1); perm[p] = i; }
}

__global__ __launch_bounds__(512, 2) void k_main(
    const u16* __restrict__ msg, const u16* __restrict__ wihb,
    const u16* __restrict__ whhb, const u16* __restrict__ wlinb,
    const float* __restrict__ bsum, const float* __restrict__ blin,
    const float* __restrict__ inorm, const int* __restrict__ nbrs,
    const int* __restrict__ degs, const int* __restrict__ perm,
    float* __restrict__ out) {
  __shared__ alignas(16) u16 Xl[32 * 136];
  __shared__ alignas(16) u16 Hl[32 * 136];
  __shared__ int nbrl[32 * 33];
  __shared__ int gidl[32];

  const int tid = threadIdx.x;
  const int w = tid >> 6;
  const int lane = tid & 63;
  const int l15 = lane & 15;
  const int g4 = lane >> 4;
  const int w16 = w * 16;
  const int gr = tid >> 4;         // gather row (node slot) 0..31
  const int gc = (tid & 15) * 8;   // gather col (elements)
  const int base = blockIdx.x * NB;

  if (tid < NB) gidl[tid] = perm[base + tid];
  __syncthreads();

  // neighbor indices into LDS, padded stride 33 (avoid 32-way bank conflict)
  {
    int i0 = tid, i1 = tid + 512;
    nbrl[(i0 >> 5) * 33 + (i0 & 31)] = nbrs[(size_t)gidl[i0 >> 5] * 32 + (i0 & 31)];
    nbrl[(i1 >> 5) * 33 + (i1 & 31)] = nbrs[(size_t)gidl[i1 >> 5] * 32 + (i1 & 31)];
  }
  // zero H (32*136 u16 = 2176 u32)
  {
    u32* hz = (u32*)Hl;
    hz[tid] = 0; hz[tid + 512] = 0; hz[tid + 1024] = 0; hz[tid + 1536] = 0;
    if (tid < 128) hz[tid + 2048] = 0;
  }
  // per-wave B fragments (row-major W rows are exactly the B-frag layout)
  short8 fih[4][4], fhh[4][4];
#pragma unroll
  for (int g = 0; g < 4; ++g)
#pragma unroll
    for (int kk = 0; kk < 4; ++kk) {
      size_t o = (size_t)(g * 128 + w16 + l15) * 128 + kk * 32 + g4 * 8;
      fih[g][kk] = *(const short8*)(wihb + o);
      fhh[g][kk] = *(const short8*)(whhb + o);
    }
  float bias[4];
#pragma unroll
  for (int g = 0; g < 4; ++g) bias[g] = bsum[g * 128 + w16 + l15];

  int dg[2][4];
#pragma unroll
  for (int r = 0; r < 2; ++r)
#pragma unroll
    for (int q = 0; q < 4; ++q) dg[r][q] = degs[gidl[r * 16 + g4 * 4 + q]];
  const int maxdeg = degs[gidl[0]];   // sorted descending -> first is WG max

  float c[2][4] = {{0, 0, 0, 0}, {0, 0, 0, 0}};
  u16 hbf[2][4] = {{0, 0, 0, 0}, {0, 0, 0, 0}};
  __syncthreads();

  short8 pf;
  { int nb = nbrl[gr * 33]; pf = *(const short8*)(msg + (size_t)nb * 128 + gc); }

  for (int t = 0; t < maxdeg; ++t) {
    // phase W: commit prefetched X tile + previous step's h
    *(short8*)(Xl + gr * 136 + gc) = pf;
    if (t > 0) {
#pragma unroll
      for (int r = 0; r < 2; ++r)
#pragma unroll
        for (int q = 0; q < 4; ++q)
          Hl[(r * 16 + g4 * 4 + q) * 136 + w16 + l15] = hbf[r][q];
    }
    __syncthreads();
    if (t + 1 < maxdeg) {  // prefetch next step's gather; completes under MFMA
      int nb = nbrl[gr * 33 + t + 1];
      pf = *(const short8*)(msg + (size_t)nb * 128 + gc);
    }

    f32x4 acc[2][4];
#pragma unroll
    for (int r = 0; r < 2; ++r)
#pragma unroll
      for (int g = 0; g < 4; ++g) acc[r][g] = (f32x4){bias[g], bias[g], bias[g], bias[g]};
#pragma unroll
    for (int kk = 0; kk < 4; ++kk) {
      short8 ax0 = *(const short8*)(Xl + l15 * 136 + kk * 32 + g4 * 8);
      short8 ax1 = *(const short8*)(Xl + (16 + l15) * 136 + kk * 32 + g4 * 8);
      short8 ah0 = *(const short8*)(Hl + l15 * 136 + kk * 32 + g4 * 8);
      short8 ah1 = *(const short8*)(Hl + (16 + l15) * 136 + kk * 32 + g4 * 8);
#pragma unroll
      for (int g = 0; g < 4; ++g) {
        acc[0][g] = __builtin_amdgcn_mfma_f32_16x16x32_bf16(ax0, fih[g][kk], acc[0][g], 0, 0, 0);
        acc[0][g] = __builtin_amdgcn_mfma_f32_16x16x32_bf16(ah0, fhh[g][kk], acc[0][g], 0, 0, 0);
        acc[1][g] = __builtin_amdgcn_mfma_f32_16x16x32_bf16(ax1, fih[g][kk], acc[1][g], 0, 0, 0);
        acc[1][g] = __builtin_amdgcn_mfma_f32_16x16x32_bf16(ah1, fhh[g][kk], acc[1][g], 0, 0, 0);
      }
    }
    // epilogue: LSTM cell (fp32 state, masked by t < deg)
#pragma unroll
    for (int r = 0; r < 2; ++r)
#pragma unroll
      for (int q = 0; q < 4; ++q) {
        float iv = sigf(acc[r][0][q]);
        float fv = sigf(acc[r][1][q]);
        float gv = tanhf_(acc[r][2][q]);
        float ov = sigf(acc[r][3][q]);
        float cn = fv * c[r][q] + iv * gv;
        float hn = ov * tanhf_(cn);
        bool act = t < dg[r][q];
        c[r][q] = act ? cn : c[r][q];
        hbf[r][q] = act ? f2bf(hn) : hbf[r][q];
      }
    __syncthreads();
  }

  // final h commit
#pragma unroll
  for (int r = 0; r < 2; ++r)
#pragma unroll
    for (int q = 0; q < 4; ++q)
      Hl[(r * 16 + g4 * 4 + q) * 136 + w16 + l15] = hbf[r][q];
  __syncthreads();

  // out = (h @ W_lin^T) / in_norm + b_lin   (wave w owns out cols 16w..16w+15)
  short8 wl[4];
#pragma unroll
  for (int kk = 0; kk < 4; ++kk)
    wl[kk] = *(const short8*)(wlinb + (size_t)(w16 + l15) * 128 + kk * 32 + g4 * 8);
  f32x4 a2[2] = {(f32x4){0, 0, 0, 0}, (f32x4){0, 0, 0, 0}};
#pragma unroll
  for (int kk = 0; kk < 4; ++kk)
#pragma unroll
    for (int r = 0; r < 2; ++r) {
      short8 ah = *(const short8*)(Hl + (r * 16 + l15) * 136 + kk * 32 + g4 * 8);
      a2[r] = __builtin_amdgcn_mfma_f32_16x16x32_bf16(ah, wl[kk], a2[r], 0, 0, 0);
    }
  float blv = blin[w16 + l15];
#pragma unroll
  for (int r = 0; r < 2; ++r)
#pragma unroll
    for (int q = 0; q < 4; ++q) {
      int nl = r * 16 + g4 * 4 + q;
      int g = gidl[nl];
      out[(size_t)g * 128 + w16 + l15] = a2[r][q] / inorm[g] + blv;
    }
}

extern "C" void kernel_launch(void* const* d_in, const int* in_sizes, int n_in,
                              void* d_out, int out_size, void* d_ws, size_t ws_size,
                              hipStream_t stream) {
  const float* feat    = (const float*)d_in[0];
  const float* in_norm = (const float*)d_in[1];
  const float* out_nrm = (const float*)d_in[2];
  const float* W_ih    = (const float*)d_in[3];
  const float* W_hh    = (const float*)d_in[4];
  const float* b_ih    = (const float*)d_in[5];
  const float* b_hh    = (const float*)d_in[6];
  const float* W_lin   = (const float*)d_in[7];
  const float* b_lin   = (const float*)d_in[8];
  const int* neighbors = (const int*)d_in[9];
  const int* degrees   = (const int*)d_in[10];
  float* out = (float*)d_out;

  char* ws = (char*)d_ws;
  u16* msg    = (u16*)(ws);                 // 51,200,000 B
  u16* wihb   = (u16*)(ws + 51200000);      //    131,072 B
  u16* whhb   = (u16*)(ws + 51331072);      //    131,072 B
  u16* wlinb  = (u16*)(ws + 51462144);      //     32,768 B
  float* bsum = (float*)(ws + 51494912);    //      2,048 B
  int* perm   = (int*)(ws + 51496960);      //    800,000 B
  int* hist   = (int*)(ws + 52296960);      // 64 ints
  int* basep  = hist + 64;                  // 33 ints
  if (ws_size < 52297600) return;           // need ~52.3 MB scratch

  hipMemsetAsync(hist, 0, 64 * 4, stream);
  k_prep_msg<<<12500, 256, 0, stream>>>(feat, out_nrm, msg);
  k_prep_w<<<578, 256, 0, stream>>>(W_ih, W_hh, W_lin, b_ih, b_hh, wihb, whhb, wlinb, bsum);
  k_hist<<<782, 256, 0, stream>>>(degrees, hist, NN);
  k_scan<<<1, 1, 0, stream>>>(hist, basep);
  k_scatter<<<782, 256, 0, stream>>>(degrees, basep, perm, NN);
  k_main<<<NWG, 512, 0, stream>>>(msg, wihb, whhb, wlinb, bsum, b_lin, in_norm,
                                  neighbors, degrees, perm, out);
}

// Round 2
// 1167.120 us; speedup vs baseline: 1.3881x; 1.3881x over previous
//
#include <hip/hip_runtime.h>

#define NN 200000
#define NB 64
#define NWG (NN / NB)   // 3125

typedef unsigned short u16;
typedef unsigned int u32;
typedef __attribute__((ext_vector_type(8))) short short8;
typedef __attribute__((ext_vector_type(4))) float f32x4;

__device__ __forceinline__ u16 f2bf(float x) {
  u32 u = __float_as_uint(x);
  u += 0x7FFFu + ((u >> 16) & 1u);
  return (u16)(u >> 16);
}
__device__ __forceinline__ float sigf(float x) {
  float e = __builtin_amdgcn_exp2f(x * -1.44269504f);
  return __builtin_amdgcn_rcpf(1.0f + e);
}
__device__ __forceinline__ float tanhf_(float x) {
  float e = __builtin_amdgcn_exp2f(x * 2.88539008f);
  return 1.0f - 2.0f * __builtin_amdgcn_rcpf(1.0f + e);
}

// msg[n][k] = bf16(feat[n][k] / out_norm[n]); 16 threads per row, 8 elems each
__global__ void k_prep_msg(const float* __restrict__ feat, const float* __restrict__ onorm,
                           u16* __restrict__ msg) {
  int i = blockIdx.x * 256 + threadIdx.x;   // 3,200,000 total, exact
  int row = i >> 4, c8 = (i & 15) * 8;
  const float4 a = *(const float4*)(feat + (size_t)row * 128 + c8);
  const float4 b = *(const float4*)(feat + (size_t)row * 128 + c8 + 4);
  float s = 1.0f / onorm[row];
  short8 v = { (short)f2bf(a.x * s), (short)f2bf(a.y * s), (short)f2bf(a.z * s), (short)f2bf(a.w * s),
               (short)f2bf(b.x * s), (short)f2bf(b.y * s), (short)f2bf(b.z * s), (short)f2bf(b.w * s) };
  *(short8*)(msg + (size_t)row * 128 + c8) = v;
}

__global__ void k_prep_w(const float* __restrict__ Wih, const float* __restrict__ Whh,
                         const float* __restrict__ Wlin, const float* __restrict__ bih,
                         const float* __restrict__ bhh, u16* __restrict__ wihb,
                         u16* __restrict__ whhb, u16* __restrict__ wlinb,
                         float* __restrict__ bsum) {
  int i = blockIdx.x * 256 + threadIdx.x;   // 147,968 total, exact
  if (i < 65536) wihb[i] = f2bf(Wih[i]);
  else if (i < 131072) whhb[i - 65536] = f2bf(Whh[i - 65536]);
  else if (i < 147456) wlinb[i - 131072] = f2bf(Wlin[i - 131072]);
  else { int j = i - 147456; bsum[j] = bih[j] + bhh[j]; }
}

__global__ void k_hist(const int* __restrict__ degs, int* __restrict__ hist, int n) {
  __shared__ int lh[33];
  if (threadIdx.x < 33) lh[threadIdx.x] = 0;
  __syncthreads();
  int i = blockIdx.x * 256 + threadIdx.x;
  if (i < n) atomicAdd(&lh[degs[i]], 1);
  __syncthreads();
  if (threadIdx.x < 33 && lh[threadIdx.x]) atomicAdd(&hist[threadIdx.x], lh[threadIdx.x]);
}

// descending-degree exclusive prefix (longest blocks scheduled first)
__global__ void k_scan(const int* __restrict__ hist, int* __restrict__ basep) {
  if (threadIdx.x == 0 && blockIdx.x == 0) {
    int a = 0;
    for (int d = 32; d >= 1; --d) { basep[d] = a; a += hist[d]; }
    basep[0] = a;
  }
}

// block-aggregated scatter: one global atomic per (block, degree) instead of per node
__global__ void k_scatter(const int* __restrict__ degs, int* __restrict__ basep,
                          int* __restrict__ perm, int n) {
  __shared__ int lh[33], lbase[33], lc[33];
  int t = threadIdx.x;
  if (t < 33) { lh[t] = 0; lc[t] = 0; }
  __syncthreads();
  int i = blockIdx.x * 256 + t;
  int d = (i < n) ? degs[i] : 0;
  if (i < n) atomicAdd(&lh[d], 1);
  __syncthreads();
  if (t < 33 && lh[t]) lbase[t] = atomicAdd(&basep[t], lh[t]);
  __syncthreads();
  if (i < n) { int r = atomicAdd(&lc[d], 1); perm[lbase[d] + r] = i; }
}

__global__ __launch_bounds__(512, 2) void k_main(
    const u16* __restrict__ msg, const u16* __restrict__ wihb,
    const u16* __restrict__ whhb, const u16* __restrict__ wlinb,
    const float* __restrict__ bsum, const float* __restrict__ blin,
    const float* __restrict__ inorm, const int* __restrict__ nbrs,
    const int* __restrict__ degs, const int* __restrict__ perm,
    float* __restrict__ out) {
  __shared__ alignas(16) u16 Xb[2][64 * 136];   // double-buffered X tile
  __shared__ alignas(16) u16 Hb[2][64 * 136];   // double-buffered H tile
  __shared__ int nbrl[64 * 33];
  __shared__ int gidl[64];

  const int tid = threadIdx.x;
  const int w = tid >> 6;
  const int lane = tid & 63;
  const int l15 = lane & 15;
  const int g4 = lane >> 4;
  const int w16 = w * 16;
  const int gr = tid >> 4;         // gather row pair: rows gr and gr+32
  const int gc = (tid & 15) * 8;
  const int base = blockIdx.x * NB;

  if (tid < NB) gidl[tid] = perm[base + tid];
  __syncthreads();

  // neighbor indices into LDS, padded stride 33
#pragma unroll
  for (int s = 0; s < 4; ++s) {
    int i = tid + s * 512;
    nbrl[(i >> 5) * 33 + (i & 31)] = nbrs[(size_t)gidl[i >> 5] * 32 + (i & 31)];
  }
  // zero Hb[0] (64*136 u16 = 4352 u32)
  {
    u32* hz = (u32*)Hb[0];
#pragma unroll
    for (int s = 0; s < 8; ++s) hz[tid + s * 512] = 0;
    if (tid < 256) hz[tid + 4096] = 0;
  }
  // per-wave B fragments (row-major W rows are exactly the B-frag layout)
  short8 fih[4][4], fhh[4][4];
#pragma unroll
  for (int g = 0; g < 4; ++g)
#pragma unroll
    for (int kk = 0; kk < 4; ++kk) {
      size_t o = (size_t)(g * 128 + w16 + l15) * 128 + kk * 32 + g4 * 8;
      fih[g][kk] = *(const short8*)(wihb + o);
      fhh[g][kk] = *(const short8*)(whhb + o);
    }
  float bias[4];
#pragma unroll
  for (int g = 0; g < 4; ++g) bias[g] = bsum[g * 128 + w16 + l15];

  // packed per-cell degrees (u8 x4 per row-frag) to save VGPRs
  u32 dgp[4];
#pragma unroll
  for (int r = 0; r < 4; ++r) {
    u32 p = 0;
#pragma unroll
    for (int q = 0; q < 4; ++q) p |= ((u32)degs[gidl[r * 16 + g4 * 4 + q]]) << (8 * q);
    dgp[r] = p;
  }
  const int maxdeg = degs[gidl[0]];   // sorted descending -> first is WG max

  float c[4][4] = {};
  u16 hbf[4][4] = {};
  __syncthreads();   // nbrl + Hb[0] ready

  // gather X(0)
  short8 pf0, pf1;
  {
    int n0 = nbrl[gr * 33], n1 = nbrl[(gr + 32) * 33];
    pf0 = *(const short8*)(msg + (size_t)n0 * 128 + gc);
    pf1 = *(const short8*)(msg + (size_t)n1 * 128 + gc);
  }
  *(short8*)(&Xb[0][gr * 136 + gc]) = pf0;
  *(short8*)(&Xb[0][(gr + 32) * 136 + gc]) = pf1;
  __syncthreads();   // invariant: X(t) in Xb[t&1], h_{t-1} in Hb[t&1]

  for (int t = 0; t < maxdeg; ++t) {
    const int cur = t & 1, nxt = cur ^ 1;
    if (t + 1 < maxdeg) {   // prefetch next gather; completes under the MFMA phases
      int n0 = nbrl[gr * 33 + t + 1], n1 = nbrl[(gr + 32) * 33 + t + 1];
      pf0 = *(const short8*)(msg + (size_t)n0 * 128 + gc);
      pf1 = *(const short8*)(msg + (size_t)n1 * 128 + gc);
    }
    // two passes over row-fragments: keeps acc at 32 regs; pass0 epilogue
    // (TRANS-heavy) overlaps pass1 MFMAs in the scheduler
#pragma unroll
    for (int rp = 0; rp < 2; ++rp) {
      f32x4 acc[2][4];
#pragma unroll
      for (int r = 0; r < 2; ++r)
#pragma unroll
        for (int g = 0; g < 4; ++g) acc[r][g] = (f32x4){bias[g], bias[g], bias[g], bias[g]};
#pragma unroll
      for (int kk = 0; kk < 4; ++kk) {
        short8 ax0 = *(const short8*)(&Xb[cur][(rp * 32 + l15) * 136 + kk * 32 + g4 * 8]);
        short8 ax1 = *(const short8*)(&Xb[cur][(rp * 32 + 16 + l15) * 136 + kk * 32 + g4 * 8]);
        short8 ah0 = *(const short8*)(&Hb[cur][(rp * 32 + l15) * 136 + kk * 32 + g4 * 8]);
        short8 ah1 = *(const short8*)(&Hb[cur][(rp * 32 + 16 + l15) * 136 + kk * 32 + g4 * 8]);
#pragma unroll
        for (int g = 0; g < 4; ++g) {
          acc[0][g] = __builtin_amdgcn_mfma_f32_16x16x32_bf16(ax0, fih[g][kk], acc[0][g], 0, 0, 0);
          acc[0][g] = __builtin_amdgcn_mfma_f32_16x16x32_bf16(ah0, fhh[g][kk], acc[0][g], 0, 0, 0);
          acc[1][g] = __builtin_amdgcn_mfma_f32_16x16x32_bf16(ax1, fih[g][kk], acc[1][g], 0, 0, 0);
          acc[1][g] = __builtin_amdgcn_mfma_f32_16x16x32_bf16(ah1, fhh[g][kk], acc[1][g], 0, 0, 0);
        }
      }
      // epilogue: LSTM cell (fp32 state, masked by t < deg)
#pragma unroll
      for (int r = 0; r < 2; ++r) {
        const int rr = rp * 2 + r;
#pragma unroll
        for (int q = 0; q < 4; ++q) {
          float iv = sigf(acc[r][0][q]);
          float fv = sigf(acc[r][1][q]);
          float gv = tanhf_(acc[r][2][q]);
          float ov = sigf(acc[r][3][q]);
          float cn = fv * c[rr][q] + iv * gv;
          float hn = ov * tanhf_(cn);
          bool act = (int)((dgp[rr] >> (8 * q)) & 255u) > t;
          c[rr][q] = act ? cn : c[rr][q];
          hbf[rr][q] = act ? f2bf(hn) : hbf[rr][q];
        }
      }
    }
    // commit next-step tiles into the alternate buffers
    if (t + 1 < maxdeg) {
      *(short8*)(&Xb[nxt][gr * 136 + gc]) = pf0;
      *(short8*)(&Xb[nxt][(gr + 32) * 136 + gc]) = pf1;
    }
#pragma unroll
    for (int rr = 0; rr < 4; ++rr)
#pragma unroll
      for (int q = 0; q < 4; ++q)
        Hb[nxt][(rr * 16 + g4 * 4 + q) * 136 + w16 + l15] = hbf[rr][q];
    __syncthreads();
  }

  // final h lives in Hb[maxdeg&1]
  const u16* Hf = Hb[maxdeg & 1];

  // out = (h @ W_lin^T) / in_norm + b_lin   (wave w owns out cols 16w..16w+15)
  short8 wl[4];
#pragma unroll
  for (int kk = 0; kk < 4; ++kk)
    wl[kk] = *(const short8*)(wlinb + (size_t)(w16 + l15) * 128 + kk * 32 + g4 * 8);
  f32x4 a2[4] = {};
#pragma unroll
  for (int kk = 0; kk < 4; ++kk)
#pragma unroll
    for (int r = 0; r < 4; ++r) {
      short8 ah = *(const short8*)(&Hf[(r * 16 + l15) * 136 + kk * 32 + g4 * 8]);
      a2[r] = __builtin_amdgcn_mfma_f32_16x16x32_bf16(ah, wl[kk], a2[r], 0, 0, 0);
    }
  float blv = blin[w16 + l15];
#pragma unroll
  for (int r = 0; r < 4; ++r)
#pragma unroll
    for (int q = 0; q < 4; ++q) {
      int nl = r * 16 + g4 * 4 + q;
      int g = gidl[nl];
      out[(size_t)g * 128 + w16 + l15] = a2[r][q] / inorm[g] + blv;
    }
}

extern "C" void kernel_launch(void* const* d_in, const int* in_sizes, int n_in,
                              void* d_out, int out_size, void* d_ws, size_t ws_size,
                              hipStream_t stream) {
  const float* feat    = (const float*)d_in[0];
  const float* in_norm = (const float*)d_in[1];
  const float* out_nrm = (const float*)d_in[2];
  const float* W_ih    = (const float*)d_in[3];
  const float* W_hh    = (const float*)d_in[4];
  const float* b_ih    = (const float*)d_in[5];
  const float* b_hh    = (const float*)d_in[6];
  const float* W_lin   = (const float*)d_in[7];
  const float* b_lin   = (const float*)d_in[8];
  const int* neighbors = (const int*)d_in[9];
  const int* degrees   = (const int*)d_in[10];
  float* out = (float*)d_out;

  char* ws = (char*)d_ws;
  u16* msg    = (u16*)(ws);                 // 51,200,000 B
  u16* wihb   = (u16*)(ws + 51200000);      //    131,072 B
  u16* whhb   = (u16*)(ws + 51331072);      //    131,072 B
  u16* wlinb  = (u16*)(ws + 51462144);      //     32,768 B
  float* bsum = (float*)(ws + 51494912);    //      2,048 B
  int* perm   = (int*)(ws + 51496960);      //    800,000 B
  int* hist   = (int*)(ws + 52296960);      // 64 ints
  int* basep  = hist + 64;                  // 33 ints
  if (ws_size < 52297600) return;           // need ~52.3 MB scratch

  hipMemsetAsync(hist, 0, 64 * 4, stream);
  k_prep_msg<<<12500, 256, 0, stream>>>(feat, out_nrm, msg);
  k_prep_w<<<578, 256, 0, stream>>>(W_ih, W_hh, W_lin, b_ih, b_hh, wihb, whhb, wlinb, bsum);
  k_hist<<<782, 256, 0, stream>>>(degrees, hist, NN);
  k_scan<<<1, 1, 0, stream>>>(hist, basep);
  k_scatter<<<782, 256, 0, stream>>>(degrees, basep, perm, NN);
  k_main<<<NWG, 512, 0, stream>>>(msg, wihb, whhb, wlinb, bsum, b_lin, in_norm,
                                  neighbors, degrees, perm, out);
}